// Round 1
// baseline (955.853 us; speedup 1.0000x reference)
//
#include <hip/hip_runtime.h>
#include <math.h>

#define TLEN (1 << 20)
#define K1_CH 32           // h-scan chunk per thread
#define K1_WU 64           // h warm-up steps (contraction 0.28^64 -> bit-exact)
#define RB 1024            // reset-chain chunk
#define NB (TLEN / RB)     // 1024 chunks
#define NCAND 32           // candidate last-reset offsets per boundary (true gap <= ~9)
#define THRESH 1e-4f

#pragma clang fp contract(off)

// consts layout: 0:w1 1:w2 2:w3 3:w4 4:dt1 5:dt2 6:d2t1 7:d2t2 8:2*w4
__global__ void k_consts(const float* __restrict__ p, float* __restrict__ c) {
#pragma clang fp contract(off)
    if (threadIdx.x == 0 && blockIdx.x == 0) {
        float w1 = (float)tanh((double)p[0]);
        float w2 = (float)tanh((double)p[1]);
        float w3 = p[2], w4 = p[3];
        float dt1 = 1.0f - w1 * w1;
        float dt2 = 1.0f - w2 * w2;
        float d2t1 = (-2.0f * w1) * dt1;
        float d2t2 = (-2.0f * w2) * dt2;
        c[0] = w1; c[1] = w2; c[2] = w3; c[3] = w4;
        c[4] = dt1; c[5] = dt2; c[6] = d2t1; c[7] = d2t2;
        c[8] = 2.0f * w4;
    }
}

// Phase 1: h (=Z) via chunked warm-up. Mirrors reference op order exactly.
__global__ void __launch_bounds__(256) k_hscan(const float* __restrict__ X,
                                               const float* __restrict__ c,
                                               float* __restrict__ Z) {
#pragma clang fp contract(off)
    long j = blockIdx.x * (long)blockDim.x + threadIdx.x;
    if (j >= TLEN / K1_CH) return;
    float w1 = c[0], w2 = c[1], w3 = c[2], w4 = c[3];
    long o = j * K1_CH;
    long b = o - K1_WU; if (b < 0) b = 0;
    long tend = o + K1_CH - 1; if (tend > (long)TLEN - 1) tend = (long)TLEN - 1;
    float h = 0.0f;
    if (o == 0) Z[0] = 0.0f;
    for (long t = b; t < tend; ++t) {
        float x = X[t];
        float t1 = w1 * x;
        float t2 = w2 * h;
        float s1 = t1 + t2;
        float t3 = (w3 * x) * x;
        float s2 = s1 + t3;
        float t4 = (w4 * h) * h;
        h = s2 + t4;
        if (t + 1 >= o) Z[t + 1] = h;
    }
}

// Phase 2: per chunk-boundary transition tables over candidate last-reset positions.
// tab[i][g] = (c_{i+1} - lastReset) when chain enters chunk i with last reset at c_i - g.
__global__ void __launch_bounds__(256) k_tables(const float* __restrict__ c,
                                                const float* __restrict__ Z,
                                                unsigned char* __restrict__ tab) {
#pragma clang fp contract(off)
    long tid = blockIdx.x * (long)blockDim.x + threadIdx.x;
    if (tid >= (long)(NB - 1) * NCAND) return;
    int i = (int)(tid / NCAND);
    int g = (int)(tid % NCAND);
    float w2 = c[1], w42 = c[8];
    long start = (long)i * RB - g; if (start < 0) start = 0;
    long end = (long)(i + 1) * RB;
    float d = 1.0f;
    long last = start;
    for (long m = start + 1; m <= end; ++m) {
        float a = w2 + w42 * Z[m - 1];
        d = d * fabsf(a);
        if (d < THRESH) { last = m; d = 1.0f; }
    }
    long delta = end - last;
    tab[(long)i * NCAND + g] = (unsigned char)(delta < 255 ? delta : 255);
}

// Phase 3: resolve exact last-reset at every chunk start. Constant tables resolve
// locally; otherwise walk back to nearest constant table (or chunk 0) and compose.
__global__ void k_rho(const unsigned char* __restrict__ tab, int* __restrict__ rho) {
    int k = blockIdx.x * blockDim.x + threadIdx.x;
    if (k >= NB) return;
    if (k == 0) { rho[0] = 0; return; }
    long r = 0;
    int jj = k - 1;
    bool found = false;
    for (; jj >= 0; --jj) {
        const unsigned char* t = &tab[(long)jj * NCAND];
        unsigned char v0 = t[0];
        bool cst = true;
        for (int g = 1; g < NCAND; ++g) { if (t[g] != v0) { cst = false; break; } }
        if (cst) { r = (long)(jj + 1) * RB - v0; found = true; break; }
    }
    if (!found) { r = 0; jj = -1; }
    for (int m = jj + 1; m < k; ++m) {
        long g = (long)m * RB - r;
        if (g < 0) g = 0;
        if (g >= NCAND) g = NCAND - 1;   // cannot happen (gap <= ~9); safety only
        r = (long)(m + 1) * RB - tab[(long)m * NCAND + g];
    }
    rho[k] = (int)r;
}

// Phase 4: replay exact decay chain per chunk, emit age[i] = i - lastReset(i).
__global__ void k_age(const float* __restrict__ c, const float* __restrict__ Z,
                      const int* __restrict__ rho, unsigned char* __restrict__ age) {
#pragma clang fp contract(off)
    int i = blockIdx.x * blockDim.x + threadIdx.x;
    if (i >= NB) return;
    float w2 = c[1], w42 = c[8];
    long ci = (long)i * RB;
    long end = (long)(i + 1) * RB; if (end > (long)TLEN - 1) end = (long)TLEN - 1;
    long r = rho[i];
    if (i == 0) age[0] = 0;
    float d = 1.0f;
    long last = r;
    for (long m = r + 1; m <= end; ++m) {
        float a = w2 + w42 * Z[m - 1];
        d = d * fabsf(a);
        if (d < THRESH) { last = m; d = 1.0f; }
        if (m > ci) age[m] = (unsigned char)(m - last);
    }
}

// Phase 5: rebuild J,H per output index from its last reset (<= ~9 steps), write out.
__global__ void __launch_bounds__(256) k_jh(const float* __restrict__ X,
                                            const float* __restrict__ Z,
                                            const float* __restrict__ c,
                                            const unsigned char* __restrict__ age,
                                            float* __restrict__ Jout,
                                            float* __restrict__ Hout) {
#pragma clang fp contract(off)
    long i = blockIdx.x * (long)blockDim.x + threadIdx.x;
    if (i >= TLEN) return;
    float w2 = c[1], dt1 = c[4], dt2 = c[5], d2t1 = c[6], d2t2 = c[7], w42 = c[8];
    int a = (i == 0) ? 0 : (int)age[i];
    float J[4] = {0.0f, 0.0f, 0.0f, 0.0f};
    float H[4][4] = {{0.0f,0.0f,0.0f,0.0f},{0.0f,0.0f,0.0f,0.0f},
                     {0.0f,0.0f,0.0f,0.0f},{0.0f,0.0f,0.0f,0.0f}};
    for (long m = i - a + 1; m <= i; ++m) {
        float x = X[m - 1];
        float h = Z[m - 1];
        float av = w2 + w42 * h;
        float d0 = x * dt1;
        float d1 = h * dt2;
        float d2 = x * x;
        float d3 = h * h;
        float G[4] = {0.0f, dt2, 0.0f, 2.0f * h};
        float HW00 = x * d2t1;
        float HW11 = h * d2t2;
        float HW[4][4] = {{HW00,0.0f,0.0f,0.0f},{0.0f,HW11,0.0f,0.0f},
                          {0.0f,0.0f,0.0f,0.0f},{0.0f,0.0f,0.0f,0.0f}};
        float Hn[4][4];
#pragma unroll
        for (int r = 0; r < 4; ++r) {
#pragma unroll
            for (int cc = 0; cc < 4; ++cc) {
                // ((Hww + outer) + outer.T) + a*H, elementwise, exact order
                Hn[r][cc] = ((HW[r][cc] + G[r] * J[cc]) + G[cc] * J[r]) + av * H[r][cc];
            }
        }
#pragma unroll
        for (int r = 0; r < 4; ++r)
#pragma unroll
            for (int cc = 0; cc < 4; ++cc) H[r][cc] = Hn[r][cc];
        float Jn0 = d0 + av * J[0];
        float Jn1 = d1 + av * J[1];
        float Jn2 = d2 + av * J[2];
        float Jn3 = d3 + av * J[3];
        J[0] = Jn0; J[1] = Jn1; J[2] = Jn2; J[3] = Jn3;
    }
    float4* Jp = (float4*)(Jout + 4 * i);
    *Jp = make_float4(J[0], J[1], J[2], J[3]);
    float4* Hp = (float4*)(Hout + 16 * i);
    Hp[0] = make_float4(H[0][0], H[0][1], H[0][2], H[0][3]);
    Hp[1] = make_float4(H[1][0], H[1][1], H[1][2], H[1][3]);
    Hp[2] = make_float4(H[2][0], H[2][1], H[2][2], H[2][3]);
    Hp[3] = make_float4(H[3][0], H[3][1], H[3][2], H[3][3]);
}

extern "C" void kernel_launch(void* const* d_in, const int* in_sizes, int n_in,
                              void* d_out, int out_size, void* d_ws, size_t ws_size,
                              hipStream_t stream) {
    const float* X = (const float*)d_in[0];
    const float* P = (const float*)d_in[1];
    float* out = (float*)d_out;
    float* Z = out;                       // [T]
    float* Jout = out + (long)TLEN;       // [T,4]
    float* Hout = out + 5l * TLEN;        // [T,4,4]

    char* ws = (char*)d_ws;
    float* consts = (float*)ws;                                   // 64 B
    int* rho = (int*)(ws + 64);                                   // NB*4 = 4 KB
    unsigned char* tab = (unsigned char*)(ws + 64 + 4096);        // (NB-1)*NCAND
    size_t tab_bytes = ((size_t)(NB - 1) * NCAND + 63) / 64 * 64;
    unsigned char* age = (unsigned char*)(ws + 64 + 4096 + tab_bytes); // TLEN bytes

    hipLaunchKernelGGL(k_consts, dim3(1), dim3(64), 0, stream, P, consts);
    hipLaunchKernelGGL(k_hscan, dim3((TLEN / K1_CH + 255) / 256), dim3(256), 0, stream,
                       X, consts, Z);
    hipLaunchKernelGGL(k_tables, dim3(((NB - 1) * NCAND + 255) / 256), dim3(256), 0, stream,
                       consts, Z, tab);
    hipLaunchKernelGGL(k_rho, dim3((NB + 255) / 256), dim3(256), 0, stream, tab, rho);
    hipLaunchKernelGGL(k_age, dim3((NB + 255) / 256), dim3(256), 0, stream,
                       consts, Z, rho, age);
    hipLaunchKernelGGL(k_jh, dim3(TLEN / 256), dim3(256), 0, stream,
                       X, Z, consts, age, Jout, Hout);
}

// Round 2
// 548.741 us; speedup vs baseline: 1.7419x; 1.7419x over previous
//
#include <hip/hip_runtime.h>
#include <math.h>

#define TLEN (1 << 20)
#define K1_CH 32           // h-scan chunk per thread
#define K1_WU 64           // h warm-up steps (contraction ~0.28^64 -> bit-exact)
#define RB 1024            // reset-chain chunk
#define NB (TLEN / RB)     // 1024 chunks
#define NCAND 16           // candidate entry gaps per chunk (true gap <= 8, proven)
#define THRESH 1e-4f

#pragma clang fp contract(off)

// consts layout: 0:w1 1:w2 2:w3 3:w4 4:dt1 5:dt2 6:d2t1 7:d2t2 8:2*w4
__global__ void k_consts(const float* __restrict__ p, float* __restrict__ c) {
#pragma clang fp contract(off)
    if (threadIdx.x == 0 && blockIdx.x == 0) {
        float w1 = (float)tanh((double)p[0]);
        float w2 = (float)tanh((double)p[1]);
        float w3 = p[2], w4 = p[3];
        float dt1 = 1.0f - w1 * w1;
        float dt2 = 1.0f - w2 * w2;
        float d2t1 = (-2.0f * w1) * dt1;
        float d2t2 = (-2.0f * w2) * dt2;
        c[0] = w1; c[1] = w2; c[2] = w3; c[3] = w4;
        c[4] = dt1; c[5] = dt2; c[6] = d2t1; c[7] = d2t2;
        c[8] = 2.0f * w4;
    }
}

// Phase 1: h (=Z) via chunked warm-up. Mirrors reference op order exactly.
__global__ void __launch_bounds__(256) k_hscan(const float* __restrict__ X,
                                               const float* __restrict__ c,
                                               float* __restrict__ Z) {
#pragma clang fp contract(off)
    long j = blockIdx.x * (long)blockDim.x + threadIdx.x;
    if (j >= TLEN / K1_CH) return;
    float w1 = c[0], w2 = c[1], w3 = c[2], w4 = c[3];
    long o = j * K1_CH;
    long b = o - K1_WU; if (b < 0) b = 0;
    long tend = o + K1_CH - 1; if (tend > (long)TLEN - 1) tend = (long)TLEN - 1;
    float h = 0.0f;
    if (o == 0) Z[0] = 0.0f;
    for (long t = b; t < tend; ++t) {
        float x = X[t];
        float t1 = w1 * x;
        float t2 = w2 * h;
        float s1 = t1 + t2;
        float t3 = (w3 * x) * x;
        float s2 = s1 + t3;
        float t4 = (w4 * h) * h;
        h = s2 + t4;
        if (t + 1 >= o) Z[t + 1] = h;
    }
}

// Phase 2: per chunk-boundary transition tables over candidate entry gaps.
// tab[i][g] = exit gap of chunk i when entering with last reset at i*RB - g.
__global__ void __launch_bounds__(256) k_tables(const float* __restrict__ c,
                                                const float* __restrict__ Z,
                                                unsigned char* __restrict__ tab) {
#pragma clang fp contract(off)
    long tid = blockIdx.x * (long)blockDim.x + threadIdx.x;
    if (tid >= (long)(NB - 1) * NCAND) return;
    int i = (int)(tid / NCAND);
    int g = (int)(tid % NCAND);
    float w2 = c[1], w42 = c[8];
    long start = (long)i * RB - g; if (start < 0) start = 0;
    long end = (long)(i + 1) * RB;
    float d = 1.0f;
    long last = start;
    for (long m = start + 1; m <= end; ++m) {
        float a = w2 + w42 * Z[m - 1];
        d = d * fabsf(a);
        if (d < THRESH) { last = m; d = 1.0f; }
    }
    long delta = end - last;
    tab[(long)i * NCAND + g] = (unsigned char)(delta < NCAND ? delta : NCAND - 1);
}

// Phase 3: parallel function-composition scan over the 1023 chunk maps.
// S[t] = m_t o m_{t-1} o ... o m_0 ; rho[k] = k*RB - S[k-1][0].
__global__ void __launch_bounds__(1024) k_scan(const unsigned char* __restrict__ tab,
                                               int* __restrict__ rho) {
    __shared__ unsigned char buf[2][NB][NCAND];   // 2 x 16 KB
    int t = threadIdx.x;
    if (t < NB - 1) {
        *((uint4*)&buf[0][t][0]) = ((const uint4*)tab)[t];
    } else {
        for (int x = 0; x < NCAND; ++x) buf[0][t][x] = (unsigned char)x;  // identity
    }
    __syncthreads();
    int cur = 0;
    for (int off = 1; off < NB; off <<= 1) {
        int nxt = cur ^ 1;
        if (t >= off) {
            const unsigned char* lo = buf[cur][t - off];
            const unsigned char* hi = buf[cur][t];
            unsigned char tmp[NCAND];
#pragma unroll
            for (int x = 0; x < NCAND; ++x) tmp[x] = hi[lo[x] & (NCAND - 1)];
#pragma unroll
            for (int x = 0; x < NCAND; ++x) buf[nxt][t][x] = tmp[x];
        } else {
#pragma unroll
            for (int x = 0; x < NCAND; ++x) buf[nxt][t][x] = buf[cur][t][x];
        }
        __syncthreads();
        cur ^= 1;
    }
    if (t == 0) rho[0] = 0;
    if (t < NB - 1) rho[t + 1] = (t + 1) * RB - (int)buf[cur][t][0];
}

// Phase 4: replay exact decay chain per chunk, emit age[i] = i - lastReset(i).
__global__ void k_age(const float* __restrict__ c, const float* __restrict__ Z,
                      const int* __restrict__ rho, unsigned char* __restrict__ age) {
#pragma clang fp contract(off)
    int i = blockIdx.x * blockDim.x + threadIdx.x;
    if (i >= NB) return;
    float w2 = c[1], w42 = c[8];
    long ci = (long)i * RB;
    long end = (long)(i + 1) * RB; if (end > (long)TLEN - 1) end = (long)TLEN - 1;
    long r = rho[i];
    if (i == 0) age[0] = 0;
    float d = 1.0f;
    long last = r;
    for (long m = r + 1; m <= end; ++m) {
        float a = w2 + w42 * Z[m - 1];
        d = d * fabsf(a);
        if (d < THRESH) { last = m; d = 1.0f; }
        if (m > ci) age[m] = (unsigned char)(m - last);
    }
}

// Phase 5: rebuild J,H per output index from its last reset (<= 8 steps), write out.
__global__ void __launch_bounds__(256) k_jh(const float* __restrict__ X,
                                            const float* __restrict__ Z,
                                            const float* __restrict__ c,
                                            const unsigned char* __restrict__ age,
                                            float* __restrict__ Jout,
                                            float* __restrict__ Hout) {
#pragma clang fp contract(off)
    long i = blockIdx.x * (long)blockDim.x + threadIdx.x;
    if (i >= TLEN) return;
    float w2 = c[1], dt1 = c[4], dt2 = c[5], d2t1 = c[6], d2t2 = c[7], w42 = c[8];
    int a = (i == 0) ? 0 : (int)age[i];
    float J[4] = {0.0f, 0.0f, 0.0f, 0.0f};
    float H[4][4] = {{0.0f,0.0f,0.0f,0.0f},{0.0f,0.0f,0.0f,0.0f},
                     {0.0f,0.0f,0.0f,0.0f},{0.0f,0.0f,0.0f,0.0f}};
    for (long m = i - a + 1; m <= i; ++m) {
        float x = X[m - 1];
        float h = Z[m - 1];
        float av = w2 + w42 * h;
        float d0 = x * dt1;
        float d1 = h * dt2;
        float d2 = x * x;
        float d3 = h * h;
        float G[4] = {0.0f, dt2, 0.0f, 2.0f * h};
        float HW00 = x * d2t1;
        float HW11 = h * d2t2;
        float HW[4][4] = {{HW00,0.0f,0.0f,0.0f},{0.0f,HW11,0.0f,0.0f},
                          {0.0f,0.0f,0.0f,0.0f},{0.0f,0.0f,0.0f,0.0f}};
        float Hn[4][4];
#pragma unroll
        for (int r = 0; r < 4; ++r) {
#pragma unroll
            for (int cc = 0; cc < 4; ++cc) {
                Hn[r][cc] = ((HW[r][cc] + G[r] * J[cc]) + G[cc] * J[r]) + av * H[r][cc];
            }
        }
#pragma unroll
        for (int r = 0; r < 4; ++r)
#pragma unroll
            for (int cc = 0; cc < 4; ++cc) H[r][cc] = Hn[r][cc];
        float Jn0 = d0 + av * J[0];
        float Jn1 = d1 + av * J[1];
        float Jn2 = d2 + av * J[2];
        float Jn3 = d3 + av * J[3];
        J[0] = Jn0; J[1] = Jn1; J[2] = Jn2; J[3] = Jn3;
    }
    float4* Jp = (float4*)(Jout + 4 * i);
    *Jp = make_float4(J[0], J[1], J[2], J[3]);
    float4* Hp = (float4*)(Hout + 16 * i);
    Hp[0] = make_float4(H[0][0], H[0][1], H[0][2], H[0][3]);
    Hp[1] = make_float4(H[1][0], H[1][1], H[1][2], H[1][3]);
    Hp[2] = make_float4(H[2][0], H[2][1], H[2][2], H[2][3]);
    Hp[3] = make_float4(H[3][0], H[3][1], H[3][2], H[3][3]);
}

extern "C" void kernel_launch(void* const* d_in, const int* in_sizes, int n_in,
                              void* d_out, int out_size, void* d_ws, size_t ws_size,
                              hipStream_t stream) {
    const float* X = (const float*)d_in[0];
    const float* P = (const float*)d_in[1];
    float* out = (float*)d_out;
    float* Z = out;                       // [T]
    float* Jout = out + (long)TLEN;       // [T,4]
    float* Hout = out + 5l * TLEN;        // [T,4,4]

    char* ws = (char*)d_ws;
    float* consts = (float*)ws;                                   // 64 B
    int* rho = (int*)(ws + 64);                                   // NB*4 = 4 KB
    unsigned char* tab = (unsigned char*)(ws + 64 + 4096);        // (NB-1)*NCAND
    size_t tab_bytes = ((size_t)(NB - 1) * NCAND + 63) / 64 * 64;
    unsigned char* age = (unsigned char*)(ws + 64 + 4096 + tab_bytes); // TLEN bytes

    hipLaunchKernelGGL(k_consts, dim3(1), dim3(64), 0, stream, P, consts);
    hipLaunchKernelGGL(k_hscan, dim3((TLEN / K1_CH + 255) / 256), dim3(256), 0, stream,
                       X, consts, Z);
    hipLaunchKernelGGL(k_tables, dim3(((NB - 1) * NCAND + 255) / 256), dim3(256), 0, stream,
                       consts, Z, tab);
    hipLaunchKernelGGL(k_scan, dim3(1), dim3(1024), 0, stream, tab, rho);
    hipLaunchKernelGGL(k_age, dim3((NB + 255) / 256), dim3(256), 0, stream,
                       consts, Z, rho, age);
    hipLaunchKernelGGL(k_jh, dim3(TLEN / 256), dim3(256), 0, stream,
                       X, Z, consts, age, Jout, Hout);
}

// Round 3
// 134.806 us; speedup vs baseline: 7.0906x; 4.0706x over previous
//
#include <hip/hip_runtime.h>
#include <math.h>

#define TLEN (1 << 20)
#define K1_CH 16           // h-scan chunk per thread
#define K1_WU 64           // h warm-up steps (contraction ~0.26^64 -> bit-exact)
#define SB 128             // reset-chain sub-chunk
#define NSB (TLEN / SB)    // 8192 sub-chunks
#define SCB 1024           // maps per scan block
#define NSCB (NSB / SCB)   // 8 scan blocks
#define NCAND 16           // candidate entry gaps (true gap <= 8, proven: |a|<=0.26)
#define THRESH 1e-4f

#pragma clang fp contract(off)

// consts layout: 0:w1 1:w2 2:w3 3:w4 4:dt1 5:dt2 6:d2t1 7:d2t2 8:2*w4
__global__ void k_consts(const float* __restrict__ p, float* __restrict__ c) {
#pragma clang fp contract(off)
    if (threadIdx.x == 0 && blockIdx.x == 0) {
        float w1 = (float)tanh((double)p[0]);
        float w2 = (float)tanh((double)p[1]);
        float w3 = p[2], w4 = p[3];
        float dt1 = 1.0f - w1 * w1;
        float dt2 = 1.0f - w2 * w2;
        float d2t1 = (-2.0f * w1) * dt1;
        float d2t2 = (-2.0f * w2) * dt2;
        c[0] = w1; c[1] = w2; c[2] = w3; c[3] = w4;
        c[4] = dt1; c[5] = dt2; c[6] = d2t1; c[7] = d2t2;
        c[8] = 2.0f * w4;
    }
}

// Phase 1: h (=Z) via chunked warm-up. Mirrors reference op order exactly.
__global__ void __launch_bounds__(256) k_hscan(const float* __restrict__ X,
                                               const float* __restrict__ c,
                                               float* __restrict__ Z) {
#pragma clang fp contract(off)
    long j = blockIdx.x * (long)blockDim.x + threadIdx.x;
    if (j >= TLEN / K1_CH) return;
    float w1 = c[0], w2 = c[1], w3 = c[2], w4 = c[3];
    long o = j * K1_CH;
    long b = o - K1_WU; if (b < 0) b = 0;
    long tend = o + K1_CH - 1; if (tend > (long)TLEN - 1) tend = (long)TLEN - 1;
    float h = 0.0f;
    if (o == 0) Z[0] = 0.0f;
    for (long t = b; t < tend; ++t) {
        float x = X[t];
        float t1 = w1 * x;
        float t2 = w2 * h;
        float s1 = t1 + t2;
        float t3 = (w3 * x) * x;
        float s2 = s1 + t3;
        float t4 = (w4 * h) * h;
        h = s2 + t4;
        if (t + 1 >= o) Z[t + 1] = h;
    }
}

// Phase 2: per sub-chunk transition maps over candidate entry gaps.
// tab[i][g] = exit gap of sub-chunk i when entering with last reset at i*SB - g.
__global__ void __launch_bounds__(256) k_tables(const float* __restrict__ c,
                                                const float* __restrict__ Z,
                                                unsigned char* __restrict__ tab) {
#pragma clang fp contract(off)
    long tid = blockIdx.x * (long)blockDim.x + threadIdx.x;
    if (tid >= (long)(NSB - 1) * NCAND) return;
    int i = (int)(tid / NCAND);
    int g = (int)(tid % NCAND);
    float w2 = c[1], w42 = c[8];
    long start = (long)i * SB - g; if (start < 0) start = 0;
    long end = (long)(i + 1) * SB;
    float d = 1.0f;
    long last = start;
    for (long m = start + 1; m <= end; ++m) {
        float a = w2 + w42 * Z[m - 1];
        d = d * fabsf(a);
        if (d < THRESH) { last = m; d = 1.0f; }
    }
    long delta = end - last;
    tab[(long)i * NCAND + g] = (unsigned char)(delta < NCAND ? delta : NCAND - 1);
}

// Phase 3a: per-block Hillis-Steele scan over map composition.
// Block b emits L[b*SCB+j] = m_{b*SCB+j} o ... o m_{b*SCB} for all j.
__global__ void __launch_bounds__(1024) k_scanA(const unsigned char* __restrict__ tab,
                                                unsigned char* __restrict__ L) {
    __shared__ unsigned char buf[2][SCB][NCAND];   // 2 x 16 KB
    int t = threadIdx.x;
    long gi = (long)blockIdx.x * SCB + t;
    if (gi < NSB - 1) {
        *((uint4*)&buf[0][t][0]) = ((const uint4*)tab)[gi];
    } else {
        for (int x = 0; x < NCAND; ++x) buf[0][t][x] = (unsigned char)x;  // identity
    }
    __syncthreads();
    int cur = 0;
    for (int off = 1; off < SCB; off <<= 1) {
        int nxt = cur ^ 1;
        if (t >= off) {
            const unsigned char* lo = buf[cur][t - off];
            const unsigned char* hi = buf[cur][t];
            unsigned char tmp[NCAND];
#pragma unroll
            for (int x = 0; x < NCAND; ++x) tmp[x] = hi[lo[x] & (NCAND - 1)];
#pragma unroll
            for (int x = 0; x < NCAND; ++x) buf[nxt][t][x] = tmp[x];
        } else {
#pragma unroll
            for (int x = 0; x < NCAND; ++x) buf[nxt][t][x] = buf[cur][t][x];
        }
        __syncthreads();
        cur ^= 1;
    }
    ((uint4*)L)[gi] = *((uint4*)&buf[cur][t][0]);
}

// Phase 3b: serially compose the 8 block totals; g0[b] = entry gap at block b start.
__global__ void k_scanB(const unsigned char* __restrict__ L, int* __restrict__ g0) {
    if (threadIdx.x == 0 && blockIdx.x == 0) {
        int e = 0;
        for (int b = 0; b < NSCB; ++b) {
            g0[b] = e;
            e = (int)L[((long)b * SCB + (SCB - 1)) * NCAND + e];
        }
    }
}

// Phase 4: replay exact decay chain per sub-chunk, emit age[i] = i - lastReset(i).
__global__ void __launch_bounds__(256) k_age(const float* __restrict__ c,
                                             const float* __restrict__ Z,
                                             const unsigned char* __restrict__ L,
                                             const int* __restrict__ g0,
                                             unsigned char* __restrict__ age) {
#pragma clang fp contract(off)
    int i = blockIdx.x * blockDim.x + threadIdx.x;
    if (i >= NSB) return;
    float w2 = c[1], w42 = c[8];
    int b = i >> 10;                 // / SCB
    int j = i & (SCB - 1);
    int eb = g0[b];
    int e = (j == 0) ? eb : (int)L[((long)(i - 1)) * NCAND + eb];
    long ci = (long)i * SB;
    long end = (long)(i + 1) * SB; if (end > (long)TLEN - 1) end = (long)TLEN - 1;
    long r = ci - e;                 // exact last reset at/before sub-chunk start
    if (i == 0) { age[0] = 0; r = 0; }
    float d = 1.0f;
    long last = r;
    for (long m = r + 1; m <= end; ++m) {
        float a = w2 + w42 * Z[m - 1];
        d = d * fabsf(a);
        if (d < THRESH) { last = m; d = 1.0f; }
        if (m > ci) age[m] = (unsigned char)(m - last);
    }
}

// Phase 5: rebuild J,H per output index from its last reset (<= 8 steps), write out.
__global__ void __launch_bounds__(256) k_jh(const float* __restrict__ X,
                                            const float* __restrict__ Z,
                                            const float* __restrict__ c,
                                            const unsigned char* __restrict__ age,
                                            float* __restrict__ Jout,
                                            float* __restrict__ Hout) {
#pragma clang fp contract(off)
    long i = blockIdx.x * (long)blockDim.x + threadIdx.x;
    if (i >= TLEN) return;
    float w2 = c[1], dt1 = c[4], dt2 = c[5], d2t1 = c[6], d2t2 = c[7], w42 = c[8];
    int a = (i == 0) ? 0 : (int)age[i];
    float J[4] = {0.0f, 0.0f, 0.0f, 0.0f};
    float H[4][4] = {{0.0f,0.0f,0.0f,0.0f},{0.0f,0.0f,0.0f,0.0f},
                     {0.0f,0.0f,0.0f,0.0f},{0.0f,0.0f,0.0f,0.0f}};
    for (long m = i - a + 1; m <= i; ++m) {
        float x = X[m - 1];
        float h = Z[m - 1];
        float av = w2 + w42 * h;
        float d0 = x * dt1;
        float d1 = h * dt2;
        float d2 = x * x;
        float d3 = h * h;
        float G[4] = {0.0f, dt2, 0.0f, 2.0f * h};
        float HW00 = x * d2t1;
        float HW11 = h * d2t2;
        float HW[4][4] = {{HW00,0.0f,0.0f,0.0f},{0.0f,HW11,0.0f,0.0f},
                          {0.0f,0.0f,0.0f,0.0f},{0.0f,0.0f,0.0f,0.0f}};
        float Hn[4][4];
#pragma unroll
        for (int r = 0; r < 4; ++r) {
#pragma unroll
            for (int cc = 0; cc < 4; ++cc) {
                Hn[r][cc] = ((HW[r][cc] + G[r] * J[cc]) + G[cc] * J[r]) + av * H[r][cc];
            }
        }
#pragma unroll
        for (int r = 0; r < 4; ++r)
#pragma unroll
            for (int cc = 0; cc < 4; ++cc) H[r][cc] = Hn[r][cc];
        float Jn0 = d0 + av * J[0];
        float Jn1 = d1 + av * J[1];
        float Jn2 = d2 + av * J[2];
        float Jn3 = d3 + av * J[3];
        J[0] = Jn0; J[1] = Jn1; J[2] = Jn2; J[3] = Jn3;
    }
    float4* Jp = (float4*)(Jout + 4 * i);
    *Jp = make_float4(J[0], J[1], J[2], J[3]);
    float4* Hp = (float4*)(Hout + 16 * i);
    Hp[0] = make_float4(H[0][0], H[0][1], H[0][2], H[0][3]);
    Hp[1] = make_float4(H[1][0], H[1][1], H[1][2], H[1][3]);
    Hp[2] = make_float4(H[2][0], H[2][1], H[2][2], H[2][3]);
    Hp[3] = make_float4(H[3][0], H[3][1], H[3][2], H[3][3]);
}

extern "C" void kernel_launch(void* const* d_in, const int* in_sizes, int n_in,
                              void* d_out, int out_size, void* d_ws, size_t ws_size,
                              hipStream_t stream) {
    const float* X = (const float*)d_in[0];
    const float* P = (const float*)d_in[1];
    float* out = (float*)d_out;
    float* Z = out;                       // [T]
    float* Jout = out + (long)TLEN;       // [T,4]
    float* Hout = out + 5l * TLEN;        // [T,4,4]

    char* ws = (char*)d_ws;
    float* consts = (float*)ws;                                   // @0, 64 B
    int* g0 = (int*)(ws + 64);                                    // @64, 64 B
    unsigned char* tab = (unsigned char*)(ws + 128);              // 8192*16 = 128 KB
    unsigned char* L = (unsigned char*)(ws + 128 + (size_t)NSB * NCAND);   // 128 KB
    unsigned char* age = (unsigned char*)(ws + 128 + 2 * (size_t)NSB * NCAND); // 1 MB

    hipLaunchKernelGGL(k_consts, dim3(1), dim3(64), 0, stream, P, consts);
    hipLaunchKernelGGL(k_hscan, dim3((TLEN / K1_CH + 255) / 256), dim3(256), 0, stream,
                       X, consts, Z);
    hipLaunchKernelGGL(k_tables, dim3(((NSB - 1) * NCAND + 255) / 256), dim3(256), 0, stream,
                       consts, Z, tab);
    hipLaunchKernelGGL(k_scanA, dim3(NSCB), dim3(SCB), 0, stream, tab, L);
    hipLaunchKernelGGL(k_scanB, dim3(1), dim3(64), 0, stream, L, g0);
    hipLaunchKernelGGL(k_age, dim3((NSB + 255) / 256), dim3(256), 0, stream,
                       consts, Z, L, g0, age);
    hipLaunchKernelGGL(k_jh, dim3(TLEN / 256), dim3(256), 0, stream,
                       X, Z, consts, age, Jout, Hout);
}

// Round 4
// 94.132 us; speedup vs baseline: 10.1544x; 1.4321x over previous
//
#include <hip/hip_runtime.h>
#include <math.h>

#define TLEN (1 << 20)
#define K1_CH 8            // h-scan outputs per thread
#define K1_WU 48           // h warm-up steps (contraction ~0.27^48 -> bit-exact)
#define SB 64              // reset-chain sub-chunk
#define NSB (TLEN / SB)    // 16384 sub-chunks
#define SCB 512            // maps per scan block
#define NSCB (NSB / SCB)   // 32 scan blocks
#define NCAND 16           // candidate entry gaps (true gap <= 8, proven: |a|<=0.27)
#define THRESH 1e-4f

#pragma clang fp contract(off)

// consts layout: 0:w1 1:w2 2:w3 3:w4 4:dt1 5:dt2 6:d2t1 7:d2t2 8:2*w4

// Phase 1: h (=Z) via chunked warm-up; also publishes consts (block0/thread0).
__global__ void __launch_bounds__(256) k_hscan(const float* __restrict__ P,
                                               const float* __restrict__ X,
                                               float* __restrict__ c,
                                               float* __restrict__ Z) {
#pragma clang fp contract(off)
    __shared__ float sc[4];
    if (threadIdx.x == 0) {
        float w1 = (float)tanh((double)P[0]);
        float w2 = (float)tanh((double)P[1]);
        sc[0] = w1; sc[1] = w2; sc[2] = P[2]; sc[3] = P[3];
        if (blockIdx.x == 0) {
            float dt1 = 1.0f - w1 * w1;
            float dt2 = 1.0f - w2 * w2;
            c[0] = w1; c[1] = w2; c[2] = P[2]; c[3] = P[3];
            c[4] = dt1; c[5] = dt2;
            c[6] = (-2.0f * w1) * dt1; c[7] = (-2.0f * w2) * dt2;
            c[8] = 2.0f * P[3];
        }
    }
    __syncthreads();
    float w1 = sc[0], w2 = sc[1], w3 = sc[2], w4 = sc[3];
    long j = blockIdx.x * (long)blockDim.x + threadIdx.x;
    long o = j * K1_CH;
    long b = o - K1_WU; if (b < 0) b = 0;
    long tend = o + K1_CH - 1; if (tend > (long)TLEN - 1) tend = (long)TLEN - 1;
    float h = 0.0f;
    if (o == 0) Z[0] = 0.0f;
    for (long t = b; t < tend; ++t) {
        float x = X[t];
        float t1 = w1 * x;
        float t2 = w2 * h;
        float s1 = t1 + t2;
        float t3 = (w3 * x) * x;
        float s2 = s1 + t3;
        float t4 = (w4 * h) * h;
        h = s2 + t4;
        if (t + 1 >= o) Z[t + 1] = h;
    }
}

// Phase 2: per sub-chunk transition maps over candidate entry gaps.
__global__ void __launch_bounds__(256) k_tables(const float* __restrict__ c,
                                                const float* __restrict__ Z,
                                                unsigned char* __restrict__ tab) {
#pragma clang fp contract(off)
    long tid = blockIdx.x * (long)blockDim.x + threadIdx.x;
    if (tid >= (long)(NSB - 1) * NCAND) return;
    int i = (int)(tid / NCAND);
    int g = (int)(tid % NCAND);
    float w2 = c[1], w42 = c[8];
    long start = (long)i * SB - g; if (start < 0) start = 0;
    long end = (long)(i + 1) * SB;
    float d = 1.0f;
    long last = start;
    for (long m = start + 1; m <= end; ++m) {
        float a = w2 + w42 * Z[m - 1];
        d = d * fabsf(a);
        if (d < THRESH) { last = m; d = 1.0f; }
    }
    long delta = end - last;
    tab[(long)i * NCAND + g] = (unsigned char)(delta < NCAND ? delta : NCAND - 1);
}

// Phase 3a: per-block Hillis-Steele scan over map composition (SCB maps/block).
__global__ void __launch_bounds__(512) k_scanA(const unsigned char* __restrict__ tab,
                                               unsigned char* __restrict__ L) {
    __shared__ unsigned char buf[2][SCB][NCAND];   // 2 x 8 KB
    int t = threadIdx.x;
    long gi = (long)blockIdx.x * SCB + t;
    if (gi < NSB - 1) {
        *((uint4*)&buf[0][t][0]) = ((const uint4*)tab)[gi];
    } else {
        for (int x = 0; x < NCAND; ++x) buf[0][t][x] = (unsigned char)x;  // identity
    }
    __syncthreads();
    int cur = 0;
    for (int off = 1; off < SCB; off <<= 1) {
        int nxt = cur ^ 1;
        if (t >= off) {
            const unsigned char* lo = buf[cur][t - off];
            const unsigned char* hi = buf[cur][t];
            unsigned char tmp[NCAND];
#pragma unroll
            for (int x = 0; x < NCAND; ++x) tmp[x] = hi[lo[x] & (NCAND - 1)];
#pragma unroll
            for (int x = 0; x < NCAND; ++x) buf[nxt][t][x] = tmp[x];
        } else {
#pragma unroll
            for (int x = 0; x < NCAND; ++x) buf[nxt][t][x] = buf[cur][t][x];
        }
        __syncthreads();
        cur ^= 1;
    }
    ((uint4*)L)[gi] = *((uint4*)&buf[cur][t][0]);
}

// Phase 3b: compose the NSCB block totals; g0[b] = entry gap at block b start.
__global__ void k_scanB(const unsigned char* __restrict__ L, int* __restrict__ g0) {
    if (threadIdx.x == 0 && blockIdx.x == 0) {
        int e = 0;
        for (int b = 0; b < NSCB; ++b) {
            g0[b] = e;
            e = (int)L[((long)b * SCB + (SCB - 1)) * NCAND + e];
        }
    }
}

// Phase 4: replay exact decay chain per sub-chunk; ages packed 4/word, uint4 stores.
// age[ci+k] convention: age at sub-chunk START included, end excluded (aligned 64B/thread).
__global__ void __launch_bounds__(256) k_age(const float* __restrict__ c,
                                             const float* __restrict__ Z,
                                             const unsigned char* __restrict__ L,
                                             const int* __restrict__ g0,
                                             unsigned int* __restrict__ age) {
#pragma clang fp contract(off)
    int i = blockIdx.x * blockDim.x + threadIdx.x;
    if (i >= NSB) return;
    float w2 = c[1], w42 = c[8];
    int e = (i == 0) ? 0 : (int)L[(long)(i - 1) * NCAND + g0[(i - 1) / SCB]];
    long ci = (long)i * SB;
    long r = ci - e;
    float d = 1.0f;
    long last = r;
    for (long m = r + 1; m <= ci; ++m) {          // advance to sub-chunk start
        float a = w2 + w42 * Z[m - 1];
        d = d * fabsf(a);
        if (d < THRESH) { last = m; d = 1.0f; }
    }
    unsigned int w[16];
    unsigned int cur = (unsigned int)(ci - last); // = e = age[ci]
    int slot = 1, wi = 0;
#pragma unroll
    for (int k = 1; k < SB; ++k) {
        long m = ci + k;
        float a = w2 + w42 * Z[m - 1];
        d = d * fabsf(a);
        if (d < THRESH) { last = m; d = 1.0f; }
        cur |= ((unsigned int)(m - last)) << (8 * slot);
        if (++slot == 4) { w[wi++] = cur; cur = 0u; slot = 0; }
    }
    uint4* dst = (uint4*)age + (long)i * 4;
    dst[0] = make_uint4(w[0], w[1], w[2], w[3]);
    dst[1] = make_uint4(w[4], w[5], w[6], w[7]);
    dst[2] = make_uint4(w[8], w[9], w[10], w[11]);
    dst[3] = make_uint4(w[12], w[13], w[14], w[15]);
}

// Phase 5: rebuild J,H; 2 consecutive outputs per thread share the warm-back chain.
// H is symmetric; H02==H22==0 identically; zero-operand adds dropped (IEEE-exact).
__global__ void __launch_bounds__(256) k_jh(const float* __restrict__ X,
                                            const float* __restrict__ Z,
                                            const float* __restrict__ c,
                                            const unsigned short* __restrict__ age2,
                                            float* __restrict__ Jout,
                                            float* __restrict__ Hout) {
#pragma clang fp contract(off)
    long i2 = blockIdx.x * (long)blockDim.x + threadIdx.x;
    if (i2 >= TLEN / 2) return;
    long q0 = 2 * i2;
    float w2 = c[1], dt1 = c[4], dt2 = c[5], d2t1 = c[6], d2t2 = c[7], w42 = c[8];
    unsigned int u = age2[i2];
    int a0 = (int)(u & 0xffu);
    int a1 = (int)(u >> 8);
    float J0 = 0, J1 = 0, J2 = 0, J3 = 0;
    float H00 = 0, H01 = 0, H03 = 0, H11 = 0, H12 = 0, H13 = 0, H23 = 0, H33 = 0;

#define JH_STEP(mm)  {                                                         \
        float x = X[(mm) - 1];                                                 \
        float h = Z[(mm) - 1];                                                 \
        float av = w2 + w42 * h;                                               \
        float g3 = 2.0f * h;                                                   \
        float g1J0 = dt2 * J0, g1J1 = dt2 * J1, g1J2 = dt2 * J2, g1J3 = dt2 * J3; \
        float g3J0 = g3 * J0, g3J1 = g3 * J1, g3J2 = g3 * J2, g3J3 = g3 * J3;  \
        float n00 = (x * d2t1) + av * H00;                                     \
        float n01 = g1J0 + av * H01;                                           \
        float n03 = g3J0 + av * H03;                                           \
        float n11 = (((h * d2t2) + g1J1) + g1J1) + av * H11;                   \
        float n12 = g1J2 + av * H12;                                           \
        float n13 = (g1J3 + g3J1) + av * H13;                                  \
        float n23 = g3J2 + av * H23;                                           \
        float n33 = (g3J3 + g3J3) + av * H33;                                  \
        H00 = n00; H01 = n01; H03 = n03; H11 = n11;                            \
        H12 = n12; H13 = n13; H23 = n23; H33 = n33;                            \
        J0 = (x * dt1) + av * J0;                                              \
        J1 = (h * dt2) + av * J1;                                              \
        J2 = (x * x) + av * J2;                                                \
        J3 = (h * h) + av * J3;                                                \
    }

#define JH_EMIT(qq)  {                                                         \
        *((float4*)(Jout + 4 * (qq))) = make_float4(J0, J1, J2, J3);           \
        float4* Hp = (float4*)(Hout + 16 * (qq));                              \
        Hp[0] = make_float4(H00, H01, 0.0f, H03);                              \
        Hp[1] = make_float4(H01, H11, H12, H13);                               \
        Hp[2] = make_float4(0.0f, H12, 0.0f, H23);                             \
        Hp[3] = make_float4(H03, H13, H23, H33);                               \
    }

    for (long m = q0 - a0 + 1; m <= q0; ++m) JH_STEP(m);
    JH_EMIT(q0);
    if (a1 == 0) {
        long q1 = q0 + 1;
        *((float4*)(Jout + 4 * q1)) = make_float4(0.f, 0.f, 0.f, 0.f);
        float4* Hp = (float4*)(Hout + 16 * q1);
        float4 z4 = make_float4(0.f, 0.f, 0.f, 0.f);
        Hp[0] = z4; Hp[1] = z4; Hp[2] = z4; Hp[3] = z4;
    } else {
        JH_STEP(q0 + 1);
        JH_EMIT(q0 + 1);
    }
#undef JH_STEP
#undef JH_EMIT
}

extern "C" void kernel_launch(void* const* d_in, const int* in_sizes, int n_in,
                              void* d_out, int out_size, void* d_ws, size_t ws_size,
                              hipStream_t stream) {
    const float* X = (const float*)d_in[0];
    const float* P = (const float*)d_in[1];
    float* out = (float*)d_out;
    float* Z = out;                       // [T]
    float* Jout = out + (long)TLEN;       // [T,4]
    float* Hout = out + 5l * TLEN;        // [T,4,4]

    char* ws = (char*)d_ws;
    float* consts = (float*)ws;                                    // @0, 64 B
    int* g0 = (int*)(ws + 64);                                     // @64, 128 B
    unsigned char* tab = (unsigned char*)(ws + 256);               // 256 KB
    unsigned char* L = (unsigned char*)(ws + 256 + (size_t)NSB * NCAND);      // 256 KB
    unsigned int* age = (unsigned int*)(ws + 256 + 2 * (size_t)NSB * NCAND);  // 1 MB

    hipLaunchKernelGGL(k_hscan, dim3(TLEN / K1_CH / 256), dim3(256), 0, stream,
                       P, X, consts, Z);
    hipLaunchKernelGGL(k_tables, dim3(((NSB - 1) * NCAND + 255) / 256), dim3(256), 0, stream,
                       consts, Z, tab);
    hipLaunchKernelGGL(k_scanA, dim3(NSCB), dim3(SCB), 0, stream, tab, L);
    hipLaunchKernelGGL(k_scanB, dim3(1), dim3(64), 0, stream, L, g0);
    hipLaunchKernelGGL(k_age, dim3(NSB / 256), dim3(256), 0, stream,
                       consts, Z, L, g0, age);
    hipLaunchKernelGGL(k_jh, dim3(TLEN / 2 / 256), dim3(256), 0, stream,
                       X, Z, consts, (const unsigned short*)age, Jout, Hout);
}

// Round 5
// 69.080 us; speedup vs baseline: 13.8369x; 1.3627x over previous
//
#include <hip/hip_runtime.h>
#include <math.h>

#define TLEN (1 << 20)
#define K1_CH 8            // h-scan outputs per thread
#define K1_WU 24           // h warm-up steps (0.26^24 ~ 1e-14 << half-ulp: bit-exact)
#define SB 32              // reset-chain sub-chunk
#define NSB (TLEN / SB)    // 32768 sub-chunks
#define SCB 512            // maps per scan block
#define NSCB (NSB / SCB)   // 64 scan blocks
#define THRESH 1e-4f
#define IDMAP 0x00FAC688u  // packed identity map: entry g -> g (3 bits each)

#pragma clang fp contract(off)

// consts layout: 0:w1 1:w2 2:w3 3:w4 4:dt1 5:dt2 6:d2t1 7:d2t2 8:2*w4

// Phase 1: h (=Z) via chunked warm-up; also publishes consts (block0/thread0).
__global__ void __launch_bounds__(256) k_hscan(const float* __restrict__ P,
                                               const float* __restrict__ X,
                                               float* __restrict__ c,
                                               float* __restrict__ Z) {
#pragma clang fp contract(off)
    __shared__ float sc[4];
    if (threadIdx.x == 0) {
        float w1 = (float)tanh((double)P[0]);
        float w2 = (float)tanh((double)P[1]);
        sc[0] = w1; sc[1] = w2; sc[2] = P[2]; sc[3] = P[3];
        if (blockIdx.x == 0) {
            float dt1 = 1.0f - w1 * w1;
            float dt2 = 1.0f - w2 * w2;
            c[0] = w1; c[1] = w2; c[2] = P[2]; c[3] = P[3];
            c[4] = dt1; c[5] = dt2;
            c[6] = (-2.0f * w1) * dt1; c[7] = (-2.0f * w2) * dt2;
            c[8] = 2.0f * P[3];
        }
    }
    __syncthreads();
    float w1 = sc[0], w2 = sc[1], w3 = sc[2], w4 = sc[3];
    long j = blockIdx.x * (long)blockDim.x + threadIdx.x;
    long o = j * K1_CH;
    long b = o - K1_WU; if (b < 0) b = 0;
    long tend = o + K1_CH - 1; if (tend > (long)TLEN - 1) tend = (long)TLEN - 1;
    float h = 0.0f;
    if (o == 0) Z[0] = 0.0f;
    for (long t = b; t < tend; ++t) {
        float x = X[t];
        float t1 = w1 * x;
        float t2 = w2 * h;
        float s1 = t1 + t2;
        float t3 = (w3 * x) * x;
        float s2 = s1 + t3;
        float t4 = (w4 * h) * h;
        h = s2 + t4;
        if (t + 1 >= o) Z[t + 1] = h;
    }
}

// Phase 2: per sub-chunk transition maps (8 entry gaps, 3-bit packed into u32).
__global__ void __launch_bounds__(256) k_tables(const float* __restrict__ c,
                                                const float* __restrict__ Z,
                                                unsigned int* __restrict__ tab32) {
#pragma clang fp contract(off)
    long tid = blockIdx.x * (long)blockDim.x + threadIdx.x;
    if (tid >= (long)(NSB - 1) * 8) return;
    int i = (int)(tid >> 3);
    int g = (int)(tid & 7);
    float w2 = c[1], w42 = c[8];
    long start = (long)i * SB - g; if (start < 0) start = 0;
    long end = (long)(i + 1) * SB;
    float d = 1.0f;
    long last = start;
    for (long m = start + 1; m <= end; ++m) {
        float a = w2 + w42 * Z[m - 1];
        d = d * fabsf(a);
        if (d < THRESH) { last = m; d = 1.0f; }
    }
    long delta = end - last; if (delta > 7) delta = 7;   // provably never clamps
    unsigned int v = (unsigned int)delta << (3 * g);
    v |= __shfl_xor(v, 1);
    v |= __shfl_xor(v, 2);
    v |= __shfl_xor(v, 4);
    if (g == 0) tab32[i] = v;
}

// Phase 3: per-block Hillis-Steele scan over packed-map composition.
// Emits L32[gi] = m_gi o ... o m_blockstart, and block totals BT[b].
__global__ void __launch_bounds__(512) k_scanA(const unsigned int* __restrict__ tab32,
                                               unsigned int* __restrict__ L32,
                                               unsigned int* __restrict__ BT) {
    __shared__ unsigned int buf[2][SCB];
    int t = threadIdx.x;
    long gi = (long)blockIdx.x * SCB + t;
    buf[0][t] = (gi < NSB - 1) ? tab32[gi] : IDMAP;
    __syncthreads();
    int cur = 0;
    for (int off = 1; off < SCB; off <<= 1) {
        unsigned int hi = buf[cur][t];
        unsigned int r;
        if (t >= off) {
            unsigned int lo = buf[cur][t - off];
            r = 0;
#pragma unroll
            for (int g = 0; g < 8; ++g) {
                unsigned int lg = (lo >> (3 * g)) & 7u;
                r |= ((hi >> (3 * lg)) & 7u) << (3 * g);
            }
        } else {
            r = hi;
        }
        buf[cur ^ 1][t] = r;
        __syncthreads();
        cur ^= 1;
    }
    L32[gi] = buf[cur][t];
    if (t == SCB - 1) BT[blockIdx.x] = buf[cur][t];
}

// Phase 4: compose block totals locally (scanB fused), then replay exact decay
// chain per sub-chunk; ages packed 4/byte-word, 2x uint4 stores per thread.
__global__ void __launch_bounds__(256) k_age(const float* __restrict__ c,
                                             const float* __restrict__ Z,
                                             const unsigned int* __restrict__ L32,
                                             const unsigned int* __restrict__ BT,
                                             unsigned int* __restrict__ age) {
#pragma clang fp contract(off)
    __shared__ unsigned int sBT[NSCB];
    int t = threadIdx.x;
    if (t < NSCB) sBT[t] = BT[t];
    __syncthreads();
    int i = blockIdx.x * blockDim.x + t;
    if (i >= NSB) return;
    float w2 = c[1], w42 = c[8];
    int e = 0;
    if (i > 0) {
        int b = (i - 1) >> 9;            // / SCB
        unsigned int g = 0;
        for (int k = 0; k < b; ++k) g = (sBT[k] >> (3 * g)) & 7u;   // g0[b]
        e = (int)((L32[i - 1] >> (3 * g)) & 7u);
    }
    long ci = (long)i * SB;
    long r = ci - e;
    float d = 1.0f;
    long last = r;
    for (long m = r + 1; m <= ci; ++m) {          // advance to sub-chunk start
        float a = w2 + w42 * Z[m - 1];
        d = d * fabsf(a);
        if (d < THRESH) { last = m; d = 1.0f; }
    }
    unsigned int w[8];
    unsigned int cw = (unsigned int)(ci - last);  // age at sub-chunk start
    int slot = 1, wi = 0;
#pragma unroll
    for (int k = 1; k < SB; ++k) {
        long m = ci + k;
        float a = w2 + w42 * Z[m - 1];
        d = d * fabsf(a);
        if (d < THRESH) { last = m; d = 1.0f; }
        cw |= ((unsigned int)(m - last)) << (8 * slot);
        if (++slot == 4) { w[wi++] = cw; cw = 0u; slot = 0; }
    }
    uint4* dst = (uint4*)age + (long)i * 2;
    dst[0] = make_uint4(w[0], w[1], w[2], w[3]);
    dst[1] = make_uint4(w[4], w[5], w[6], w[7]);
}

// Phase 5: rebuild J,H; 2 consecutive outputs per thread share the warm-back chain.
// H symmetric, H02==H22==0; post-reset first step peeled (J=H=0 degenerates).
__global__ void __launch_bounds__(256) k_jh(const float* __restrict__ X,
                                            const float* __restrict__ Z,
                                            const float* __restrict__ c,
                                            const unsigned short* __restrict__ age2,
                                            float* __restrict__ Jout,
                                            float* __restrict__ Hout) {
#pragma clang fp contract(off)
    long i2 = blockIdx.x * (long)blockDim.x + threadIdx.x;
    if (i2 >= TLEN / 2) return;
    long q0 = 2 * i2;
    float w2 = c[1], dt1 = c[4], dt2 = c[5], d2t1 = c[6], d2t2 = c[7], w42 = c[8];
    unsigned int u = age2[i2];
    int a0 = (int)(u & 0xffu);
    int a1 = (int)(u >> 8);
    float J0 = 0, J1 = 0, J2 = 0, J3 = 0;
    float H00 = 0, H01 = 0, H03 = 0, H11 = 0, H12 = 0, H13 = 0, H23 = 0, H33 = 0;

#define JH_SIMPLE(mm) {                                                        \
        float x = X[(mm) - 1];                                                 \
        float h = Z[(mm) - 1];                                                 \
        H00 = x * d2t1; H11 = h * d2t2;                                        \
        J0 = x * dt1; J1 = h * dt2; J2 = x * x; J3 = h * h;                    \
    }

#define JH_STEP(mm)  {                                                         \
        float x = X[(mm) - 1];                                                 \
        float h = Z[(mm) - 1];                                                 \
        float av = w2 + w42 * h;                                               \
        float g3 = 2.0f * h;                                                   \
        float g1J0 = dt2 * J0, g1J1 = dt2 * J1, g1J2 = dt2 * J2, g1J3 = dt2 * J3; \
        float g3J0 = g3 * J0, g3J1 = g3 * J1, g3J2 = g3 * J2, g3J3 = g3 * J3;  \
        float n00 = (x * d2t1) + av * H00;                                     \
        float n01 = g1J0 + av * H01;                                           \
        float n03 = g3J0 + av * H03;                                           \
        float n11 = (((h * d2t2) + g1J1) + g1J1) + av * H11;                   \
        float n12 = g1J2 + av * H12;                                           \
        float n13 = (g1J3 + g3J1) + av * H13;                                  \
        float n23 = g3J2 + av * H23;                                           \
        float n33 = (g3J3 + g3J3) + av * H33;                                  \
        H00 = n00; H01 = n01; H03 = n03; H11 = n11;                            \
        H12 = n12; H13 = n13; H23 = n23; H33 = n33;                            \
        J0 = (x * dt1) + av * J0;                                              \
        J1 = (h * dt2) + av * J1;                                              \
        J2 = (x * x) + av * J2;                                                \
        J3 = (h * h) + av * J3;                                                \
    }

#define JH_EMIT(qq)  {                                                         \
        *((float4*)(Jout + 4 * (qq))) = make_float4(J0, J1, J2, J3);           \
        float4* Hp = (float4*)(Hout + 16 * (qq));                              \
        Hp[0] = make_float4(H00, H01, 0.0f, H03);                              \
        Hp[1] = make_float4(H01, H11, H12, H13);                               \
        Hp[2] = make_float4(0.0f, H12, 0.0f, H23);                             \
        Hp[3] = make_float4(H03, H13, H23, H33);                               \
    }

    if (a0 > 0) {
        long m0 = q0 - a0 + 1;
        JH_SIMPLE(m0);
        for (long m = m0 + 1; m <= q0; ++m) JH_STEP(m);
    }
    JH_EMIT(q0);
    if (a1 == 0) {
        long q1 = q0 + 1;
        float4 z4 = make_float4(0.f, 0.f, 0.f, 0.f);
        *((float4*)(Jout + 4 * q1)) = z4;
        float4* Hp = (float4*)(Hout + 16 * q1);
        Hp[0] = z4; Hp[1] = z4; Hp[2] = z4; Hp[3] = z4;
    } else {
        if (a1 == 1) { JH_SIMPLE(q0 + 1); }
        else         { JH_STEP(q0 + 1); }
        JH_EMIT(q0 + 1);
    }
#undef JH_SIMPLE
#undef JH_STEP
#undef JH_EMIT
}

extern "C" void kernel_launch(void* const* d_in, const int* in_sizes, int n_in,
                              void* d_out, int out_size, void* d_ws, size_t ws_size,
                              hipStream_t stream) {
    const float* X = (const float*)d_in[0];
    const float* P = (const float*)d_in[1];
    float* out = (float*)d_out;
    float* Z = out;                       // [T]
    float* Jout = out + (long)TLEN;       // [T,4]
    float* Hout = out + 5l * TLEN;        // [T,4,4]

    char* ws = (char*)d_ws;
    float* consts = (float*)ws;                                    // @0, 64 B
    unsigned int* BT = (unsigned int*)(ws + 64);                   // 64 dwords
    unsigned int* tab32 = (unsigned int*)(ws + 512);               // 128 KB
    unsigned int* L32 = (unsigned int*)(ws + 512 + (size_t)NSB * 4);          // 128 KB
    unsigned int* age = (unsigned int*)(ws + 512 + 2 * (size_t)NSB * 4);      // 1 MB

    hipLaunchKernelGGL(k_hscan, dim3(TLEN / K1_CH / 256), dim3(256), 0, stream,
                       P, X, consts, Z);
    hipLaunchKernelGGL(k_tables, dim3(((NSB - 1) * 8 + 255) / 256), dim3(256), 0, stream,
                       consts, Z, tab32);
    hipLaunchKernelGGL(k_scanA, dim3(NSCB), dim3(SCB), 0, stream, tab32, L32, BT);
    hipLaunchKernelGGL(k_age, dim3(NSB / 256), dim3(256), 0, stream,
                       consts, Z, L32, BT, age);
    hipLaunchKernelGGL(k_jh, dim3(TLEN / 2 / 256), dim3(256), 0, stream,
                       X, Z, consts, (const unsigned short*)age, Jout, Hout);
}